// Round 1
// baseline (207.128 us; speedup 1.0000x reference)
//
#include <hip/hip_runtime.h>
#include <stdint.h>

#define B_   2
#define N_   16384
#define S_   4096
#define D2_  256
#define CIN_ 397
#define KP_  416      // Cin padded to 13*32 for MFMA K-slabs
#define C_   128
#define OC_  13
#define NCHUNK_ 16
#define CHS_ (S_ / NCHUNK_)       // 256 points per scan chunk
#define NCAND_ (NCHUNK_ * 3)      // 48 candidates per query
#define XBI_P 296                 // xbi LDS pitch in u16

typedef unsigned short u16;
typedef unsigned int u32;
typedef short s16x8 __attribute__((ext_vector_type(8)));
typedef float f32x4 __attribute__((ext_vector_type(4)));

#define MFMA16(a, b, c) __builtin_amdgcn_mfma_f32_16x16x32_bf16((a), (b), (c), 0, 0, 0)

__device__ __forceinline__ float b2f(u16 h) {
  union { unsigned int u; float f; } v; v.u = ((unsigned int)h) << 16; return v.f;
}
__device__ __forceinline__ u16 f2b(float f) {
  union { float f; unsigned int u; } v; v.f = f;
  unsigned int r = v.u + 0x7fffu + ((v.u >> 16) & 1u);
  return (u16)(r >> 16);
}

// 5-op branchless sorted-top3 insert on u32 keys
#define INS3U32(k0, k1, k2, key)            \
  do {                                      \
    u32 _t1 = max(k0, key);                 \
    u32 _t2 = max(k1, key);                 \
    k0 = min(k0, key);                      \
    k1 = min(k1, _t1);                      \
    k2 = min(k2, _t2);                      \
  } while (0)

// ---------------------------------------------------------------------------
// setup_scan: ONE launch. Blocks [0,1024): knn scan (2 queries/thread so each
// LDS point-read serves two queries -> LDS-pipe cycles halved).
// [1024,2048): transpose points1 -> npT. [2048,2560): transpose points2 ->
// p2t. [2560,2624): prep weights/bn.
// ---------------------------------------------------------------------------
__device__ __forceinline__ void transpose_body(
    const float* __restrict__ in, u16* __restrict__ out,
    int C, int S, int opitch, int b, int s0, int c0,
    float* __restrict__ tile, int tr, int tc4) {
  const float* ip = in + (size_t)b * C * S;
  u16* op = out + (size_t)b * S * opitch;
#pragma unroll
  for (int r = 0; r < 64; r += 16) {
    float4 v = *(const float4*)(ip + (size_t)(c0 + tr + r) * S + s0 + tc4);
    tile[(tr + r) * 65 + tc4 + 0] = v.x;
    tile[(tr + r) * 65 + tc4 + 1] = v.y;
    tile[(tr + r) * 65 + tc4 + 2] = v.z;
    tile[(tr + r) * 65 + tc4 + 3] = v.w;
  }
  __syncthreads();
#pragma unroll
  for (int r = 0; r < 64; r += 16) {
    ushort4 v;
    v.x = f2b(tile[(tc4 + 0) * 65 + tr + r]);
    v.y = f2b(tile[(tc4 + 1) * 65 + tr + r]);
    v.z = f2b(tile[(tc4 + 2) * 65 + tr + r]);
    v.w = f2b(tile[(tc4 + 3) * 65 + tr + r]);
    *(ushort4*)(op + (size_t)(s0 + tr + r) * opitch + c0 + tc4) = v;
  }
}

__global__ __launch_bounds__(256) void setup_scan_kernel(
    const float* __restrict__ xyz1, const float* __restrict__ xyz2,
    const float* __restrict__ points1, const float* __restrict__ points2,
    const float* __restrict__ fW, const float* __restrict__ fb,
    const float* __restrict__ fbn,
    const float* __restrict__ e1W, const float* __restrict__ e1b,
    const float* __restrict__ e1bn,
    const float* __restrict__ e2W, const float* __restrict__ e2b,
    const float* __restrict__ e2bn,
    const float* __restrict__ p1W, const float* __restrict__ p1b,
    const float* __restrict__ p1bn,
    const float* __restrict__ p2W, const float* __restrict__ p2b,
    const float* __restrict__ p2bn,
    u16* __restrict__ cand, u16* __restrict__ npT, u16* __restrict__ p2t,
    u16* __restrict__ Wf, u16* __restrict__ W1o,
    u16* __restrict__ W2o, u16* __restrict__ W3o,
    u16* __restrict__ Wp2, float* __restrict__ st) {
  __shared__ __align__(16) float smem[64 * 65];
  int id = blockIdx.x;
  int tid = threadIdx.x;

  if (id < 1024) {
    // ---- knn scan: 2 queries/thread, branchless, A/B top-3 sets/query ----
    float4* pts = (float4*)smem;
    int chunk = id & 15;
    int ny = (id >> 4) & 31;
    int b = id >> 9;
    int s0 = chunk * CHS_;
    const float* x2 = xyz2 + ((size_t)b * S_ + s0) * 3;
    {
      float xx = x2[tid * 3], yy = x2[tid * 3 + 1], zz = x2[tid * 3 + 2];
      pts[tid] = make_float4(xx, yy, zz, fmaf(xx, xx, fmaf(yy, yy, zz * zz)));
    }
    __syncthreads();
    int nA = ny * 512 + tid;
    int nB = nA + 256;
    const float* x1a = xyz1 + ((size_t)b * N_ + nA) * 3;
    const float* x1b = xyz1 + ((size_t)b * N_ + nB) * 3;
    float axA = x1a[0], ayA = x1a[1], azA = x1a[2];
    float axB = x1b[0], ayB = x1b[1], azB = x1b[2];
    float n1A = fmaf(axA, axA, fmaf(ayA, ayA, azA * azA));
    float n1B = fmaf(axB, axB, fmaf(ayB, ayB, azB * azB));
    u32 a0 = ~0u, a1 = ~0u, a2 = ~0u, b0 = ~0u, b1 = ~0u, b2 = ~0u;
    u32 c0 = ~0u, c1 = ~0u, c2 = ~0u, d0 = ~0u, d1 = ~0u, d2 = ~0u;
#pragma unroll 2
    for (int s = 0; s < CHS_; s += 2) {
      float4 p = pts[s];
      float4 q = pts[s + 1];
      float dpA = fmaf(axA, p.x, fmaf(ayA, p.y, azA * p.z));
      float dqA = fmaf(axA, q.x, fmaf(ayA, q.y, azA * q.z));
      float dpB = fmaf(axB, p.x, fmaf(ayB, p.y, azB * p.z));
      float dqB = fmaf(axB, q.x, fmaf(ayB, q.y, azB * q.z));
      float daA = fmaxf(fmaf(-2.f, dpA, n1A + p.w), 0.f);
      float dbA = fmaxf(fmaf(-2.f, dqA, n1A + q.w), 0.f);
      float daB = fmaxf(fmaf(-2.f, dpB, n1B + p.w), 0.f);
      float dbB = fmaxf(fmaf(-2.f, dqB, n1B + q.w), 0.f);
      u32 kaA = (__float_as_uint(daA) & 0xFFFFFF00u) | (u32)s;
      u32 kbA = (__float_as_uint(dbA) & 0xFFFFFF00u) | (u32)(s + 1);
      u32 kaB = (__float_as_uint(daB) & 0xFFFFFF00u) | (u32)s;
      u32 kbB = (__float_as_uint(dbB) & 0xFFFFFF00u) | (u32)(s + 1);
      INS3U32(a0, a1, a2, kaA);
      INS3U32(b0, b1, b2, kbA);
      INS3U32(c0, c1, c2, kaB);
      INS3U32(d0, d1, d2, kbB);
    }
    INS3U32(a0, a1, a2, b0);
    INS3U32(a0, a1, a2, b1);
    INS3U32(a0, a1, a2, b2);
    INS3U32(c0, c1, c2, d0);
    INS3U32(c0, c1, c2, d1);
    INS3U32(c0, c1, c2, d2);
    u16* coA = cand + ((size_t)(b * N_ + nA)) * NCAND_ + chunk * 3;
    coA[0] = (u16)((a0 & 0xFFu) + s0);
    coA[1] = (u16)((a1 & 0xFFu) + s0);
    coA[2] = (u16)((a2 & 0xFFu) + s0);
    u16* coB = cand + ((size_t)(b * N_ + nB)) * NCAND_ + chunk * 3;
    coB[0] = (u16)((c0 & 0xFFu) + s0);
    coB[1] = (u16)((c1 & 0xFFu) + s0);
    coB[2] = (u16)((c2 & 0xFFu) + s0);
    return;
  }

  int tr = tid >> 4;
  int tc4 = (tid & 15) * 4;
  if (id < 2048) {
    int id2 = id - 1024;
    int sx = id2 & 255, sy = (id2 >> 8) & 1, b = id2 >> 9;
    transpose_body(points1, npT, 128, N_, 128, b, sx * 64, sy * 64, smem, tr, tc4);
    return;
  }
  if (id < 2560) {
    int id2 = id - 2048;
    int sx = id2 & 63, sy = (id2 >> 6) & 3, b = id2 >> 8;
    transpose_body(points2, p2t, 256, S_, 256, b, sx * 64, sy * 64, smem, tr, tc4);
    return;
  }
  int t = (id - 2560) * 256 + tid;
  int stride = 64 * 256;
  for (int i = t; i < 128 * KP_; i += stride) {
    int m = i / KP_, k = i - m * KP_;
    Wf[i] = (k < CIN_) ? f2b(fW[m * CIN_ + k]) : (u16)0;
  }
  for (int i = t; i < 128 * 128; i += stride) {
    W1o[i] = f2b(e1W[i]);
    W2o[i] = f2b(e2W[i]);
    W3o[i] = f2b(p1W[i]);
  }
  for (int i = t; i < 16 * 128; i += stride) {
    int m = i >> 7;
    Wp2[i] = (m < OC_) ? f2b(p2W[i]) : (u16)0;
  }
  for (int i = t; i < 5 * 128; i += stride) {
    int sg = i >> 7, c = i & 127;
    const float* bn; const float* bc; int Cc = 128;
    switch (sg) {
      case 0: bn = fbn;  bc = fb;  break;
      case 1: bn = e1bn; bc = e1b; break;
      case 2: bn = e2bn; bc = e2b; break;
      case 3: bn = p1bn; bc = p1b; break;
      default: bn = p2bn; bc = p2b; Cc = OC_; break;
    }
    float s = 0.f, tt = 0.f;
    if (c < Cc) {
      float g  = bn[0 * Cc + c], be = bn[1 * Cc + c];
      float mu = bn[2 * Cc + c], vv = bn[3 * Cc + c];
      float inv = 1.0f / sqrtf(vv + 1e-5f);
      s = g * inv;
      tt = (bc[c] - mu) * s + be;
    }
    st[sg * 256 + c] = s;
    st[sg * 256 + 128 + c] = tt;
  }
}

// ---------------------------------------------------------------------------
// f64 lexicographic (d, idx) top-3 insert -- matches stable top_k semantics
// ---------------------------------------------------------------------------
__device__ __forceinline__ void ins3(double d, int i,
                                     double& D0, double& D1, double& D2,
                                     int& I0, int& I1, int& I2) {
  if ((d < D2) || (d == D2 && i < I2)) {
    if ((d < D1) || (d == D1 && i < I1)) {
      D2 = D1; I2 = I1;
      if ((d < D0) || (d == D0 && i < I0)) { D1 = D0; I1 = I0; D0 = d; I0 = i; }
      else                                  { D1 = d; I1 = i; }
    } else { D2 = d; I2 = i; }
  }
}

// ---------------------------------------------------------------------------
// mega: 32-point tile, 1024 blocks, 4 blocks/CU.
// Restructured front-end: entirely per-wave (zero block barriers before
// stage 1). 8 lanes per query do the f64 refine; top-3 merged with a 3-round
// shfl_xor butterfly (order-independent: (d,idx) pairs distinct); idx/weights
// broadcast via v_readlane (SGPR). Stage-1 npT B-fragments prefetched into
// registers at kernel entry so their HBM latency hides under refine+interp.
// sched_barrier(0) fences pin the batched gather groups so the scheduler
// cannot serialize them (VGPR_Count=52 previously proved it did).
// MFMA 16x16x32 bf16; A[m=lane&15][k=(lane>>4)*8+j]; D col=lane&15, row=q*4+r
// ---------------------------------------------------------------------------
__device__ __forceinline__ void gemm32(const u16* __restrict__ W, const u16* xb,
                                       int l15, int lq, int wv, f32x4 acc[2][2]) {
#pragma unroll
  for (int mtl = 0; mtl < 2; ++mtl) {
    acc[mtl][0] = (f32x4){0.f, 0.f, 0.f, 0.f};
    acc[mtl][1] = (f32x4){0.f, 0.f, 0.f, 0.f};
  }
#pragma unroll
  for (int ks = 0; ks < 4; ++ks) {
    int ko = ks * 32 + lq * 8;
    s16x8 b0 = *(const s16x8*)(xb + l15 * 136 + ko);
    s16x8 b1 = *(const s16x8*)(xb + (16 + l15) * 136 + ko);
#pragma unroll
    for (int mtl = 0; mtl < 2; ++mtl) {
      s16x8 a = *(const s16x8*)(W + (size_t)((wv * 2 + mtl) * 16 + l15) * 128 + ko);
      acc[mtl][0] = MFMA16(a, b0, acc[mtl][0]);
      acc[mtl][1] = MFMA16(a, b1, acc[mtl][1]);
    }
  }
}

__global__ __launch_bounds__(256, 4) void mega_kernel(
    const float* __restrict__ xyz1, const float* __restrict__ xyz2,
    const u16* __restrict__ cand,
    const u16* __restrict__ npT, const u16* __restrict__ p2t,
    const float* __restrict__ last_pred,
    const u16* __restrict__ Wf,
    const u16* __restrict__ W1, const u16* __restrict__ W2,
    const u16* __restrict__ W3, const u16* __restrict__ Wp2,
    const float* __restrict__ st, float* __restrict__ out) {
  __shared__ __align__(16) u16 xb0[32 * 136];
  __shared__ __align__(16) u16 xb1[32 * 136];
  __shared__ u16 xbi[32 * XBI_P];
  int b = blockIdx.y;
  int n0 = blockIdx.x * 32;
  int tid = threadIdx.x;
  int wv = tid >> 6, lane = tid & 63;
  int l15 = lane & 15, lq = lane >> 4;
  f32x4 acc[2][2];

  // ---- early prefetch: stage-1 npT B-fragments (independent of phases) ----
  const u16* brow0 = npT + ((size_t)(b * N_ + n0 + l15)) * 128;
  const u16* brow1 = brow0 + (size_t)16 * 128;
  s16x8 pf0[4], pf1[4];
#pragma unroll
  for (int ks = 0; ks < 4; ++ks) {
    int ko = ks * 32 + lq * 8;
    pf0[ks] = *(const s16x8*)(brow0 + ko);
    pf1[ks] = *(const s16x8*)(brow1 + ko);
  }
  __builtin_amdgcn_sched_barrier(0);

  // ---- per-wave refine: 8 lanes/query, f64 exact top-3, butterfly merge ----
  double D0, D1, D2v;
  int I0, I1, I2;
  float w0f, w1f, w2f;
  {
#pragma clang fp contract(off)
    int qi = tid >> 3, part = tid & 7;
    int qg = b * N_ + n0 + qi;
    const u16* ci = cand + (size_t)qg * NCAND_ + part * 6;
    const float* x2b = xyz2 + (size_t)b * S_ * 3;
    int ii[6];
#pragma unroll
    for (int j = 0; j < 6; ++j) ii[j] = ci[j];
    float pcx[6], pcy[6], pcz[6];
#pragma unroll
    for (int j = 0; j < 6; ++j) {
      const float* p = x2b + (size_t)ii[j] * 3;
      pcx[j] = p[0]; pcy[j] = p[1]; pcz[j] = p[2];
    }
    __builtin_amdgcn_sched_barrier(0);
    const float* x1 = xyz1 + (size_t)qg * 3;
    double ax = x1[0], ay = x1[1], az = x1[2];
    double n1 = (ax * ax + ay * ay) + az * az;
    D0 = 1e300; D1 = 1e300; D2v = 1e300;
    I0 = 2147483647; I1 = 2147483647; I2 = 2147483647;
#pragma unroll
    for (int j = 0; j < 6; ++j) {
      double px = pcx[j], py = pcy[j], pz = pcz[j];
      double n2 = (px * px + py * py) + pz * pz;
      double dot = (ax * px + ay * py) + az * pz;
      double d = (n1 + n2) - 2.0 * dot;
      ins3(d, ii[j], D0, D1, D2v, I0, I1, I2);
    }
    // butterfly merge across the 8 lanes of this query's group
#pragma unroll
    for (int r = 0; r < 3; ++r) {
      int m = 1 << r;
      double e0 = __shfl_xor(D0, m);
      double e1 = __shfl_xor(D1, m);
      double e2 = __shfl_xor(D2v, m);
      int j0 = __shfl_xor(I0, m);
      int j1 = __shfl_xor(I1, m);
      int j2 = __shfl_xor(I2, m);
      ins3(e0, j0, D0, D1, D2v, I0, I1, I2);
      ins3(e1, j1, D0, D1, D2v, I0, I1, I2);
      ins3(e2, j2, D0, D1, D2v, I0, I1, I2);
    }
    double r0 = 1.0 / (D0 + 1e-8);
    double r1 = 1.0 / (D1 + 1e-8);
    double r2 = 1.0 / (D2v + 1e-8);
    double sum = (r0 + r1) + r2;
    w0f = (float)(r0 / sum);
    w1f = (float)(r1 / sum);
    w2f = (float)(r2 / sum);
  }

  // ---- prologue: batch-gather 24 p2t rows (readlane broadcast of indices),
  //      then interpolate into xbi. No block barrier needed before this:
  //      each wave consumes only its own 8 queries. ----
  {
    const float* lpb = last_pred + (size_t)b * S_ * OC_;
    const u16* p2b = p2t + (size_t)b * S_ * D2_;
    ushort4 g0[8], g1[8], g2[8];
#pragma unroll
    for (int i = 0; i < 8; ++i) {
      int i0 = __builtin_amdgcn_readlane(I0, i * 8);
      int i1 = __builtin_amdgcn_readlane(I1, i * 8);
      int i2 = __builtin_amdgcn_readlane(I2, i * 8);
      g0[i] = *(const ushort4*)(p2b + (size_t)i0 * D2_ + lane * 4);
      g1[i] = *(const ushort4*)(p2b + (size_t)i1 * D2_ + lane * 4);
      g2[i] = *(const ushort4*)(p2b + (size_t)i2 * D2_ + lane * 4);
    }
    __builtin_amdgcn_sched_barrier(0);
#pragma unroll
    for (int i = 0; i < 8; ++i) {
      int p = wv * 8 + i;
      float w0 = __uint_as_float(__builtin_amdgcn_readlane(__float_as_uint(w0f), i * 8));
      float w1 = __uint_as_float(__builtin_amdgcn_readlane(__float_as_uint(w1f), i * 8));
      float w2 = __uint_as_float(__builtin_amdgcn_readlane(__float_as_uint(w2f), i * 8));
      int i0 = __builtin_amdgcn_readlane(I0, i * 8);
      int i1 = __builtin_amdgcn_readlane(I1, i * 8);
      int i2 = __builtin_amdgcn_readlane(I2, i * 8);
      ushort4 v;
      v.x = f2b((w0 * b2f(g0[i].x) + w1 * b2f(g1[i].x)) + w2 * b2f(g2[i].x));
      v.y = f2b((w0 * b2f(g0[i].y) + w1 * b2f(g1[i].y)) + w2 * b2f(g2[i].y));
      v.z = f2b((w0 * b2f(g0[i].z) + w1 * b2f(g1[i].z)) + w2 * b2f(g2[i].z));
      v.w = f2b((w0 * b2f(g0[i].w) + w1 * b2f(g1[i].w)) + w2 * b2f(g2[i].w));
      *(ushort4*)(&xbi[p * XBI_P + lane * 4]) = v;
      u16 pv = 0;
      if (lane < OC_) {
        pv = f2b((w0 * lpb[(size_t)i0 * OC_ + lane] + w1 * lpb[(size_t)i1 * OC_ + lane])
                 + w2 * lpb[(size_t)i2 * OC_ + lane]);
      }
      if (lane < 32) xbi[p * XBI_P + 256 + lane] = pv;   // cols 256..287 (k=384..415)
    }
  }
  __syncthreads();

  // ---- stage 1: fuse (K=416): k<128 from prefetched npT regs, rest xbi ----
#pragma unroll
  for (int mtl = 0; mtl < 2; ++mtl) {
    acc[mtl][0] = (f32x4){0.f, 0.f, 0.f, 0.f};
    acc[mtl][1] = (f32x4){0.f, 0.f, 0.f, 0.f};
  }
  {
#pragma unroll
    for (int ks = 0; ks < 4; ++ks) {
      int ko = ks * 32 + lq * 8;
#pragma unroll
      for (int mtl = 0; mtl < 2; ++mtl) {
        s16x8 a = *(const s16x8*)(Wf + (size_t)((wv * 2 + mtl) * 16 + l15) * KP_ + ko);
        acc[mtl][0] = MFMA16(a, pf0[ks], acc[mtl][0]);
        acc[mtl][1] = MFMA16(a, pf1[ks], acc[mtl][1]);
      }
    }
#pragma unroll 1
    for (int ks = 0; ks < 9; ++ks) {
      int kk = ks * 32 + lq * 8;
      s16x8 bf0 = *(const s16x8*)(&xbi[l15 * XBI_P + kk]);
      s16x8 bf1 = *(const s16x8*)(&xbi[(16 + l15) * XBI_P + kk]);
#pragma unroll
      for (int mtl = 0; mtl < 2; ++mtl) {
        s16x8 a = *(const s16x8*)(Wf + (size_t)((wv * 2 + mtl) * 16 + l15) * KP_ + 128 + kk);
        acc[mtl][0] = MFMA16(a, bf0, acc[mtl][0]);
        acc[mtl][1] = MFMA16(a, bf1, acc[mtl][1]);
      }
    }
  }
#pragma unroll
  for (int mtl = 0; mtl < 2; ++mtl) {
    int m4 = (wv * 2 + mtl) * 16 + lq * 4;
    f32x4 sc = *(const f32x4*)(st + 0 * 256 + m4);
    f32x4 bi = *(const f32x4*)(st + 0 * 256 + 128 + m4);
#pragma unroll
    for (int nt = 0; nt < 2; ++nt) {
      int n_l = nt * 16 + l15;
      ushort4 v;
      v.x = f2b(fmaxf(acc[mtl][nt][0] * sc[0] + bi[0], 0.f));
      v.y = f2b(fmaxf(acc[mtl][nt][1] * sc[1] + bi[1], 0.f));
      v.z = f2b(fmaxf(acc[mtl][nt][2] * sc[2] + bi[2], 0.f));
      v.w = f2b(fmaxf(acc[mtl][nt][3] * sc[3] + bi[3], 0.f));
      *(ushort4*)(&xb0[n_l * 136 + m4]) = v;
    }
  }
  __syncthreads();

  // ---- stage 2: ext1 (K=128), xb0 -> xb1 ----
  gemm32(W1, xb0, l15, lq, wv, acc);
#pragma unroll
  for (int mtl = 0; mtl < 2; ++mtl) {
    int m4 = (wv * 2 + mtl) * 16 + lq * 4;
    f32x4 sc = *(const f32x4*)(st + 1 * 256 + m4);
    f32x4 bi = *(const f32x4*)(st + 1 * 256 + 128 + m4);
#pragma unroll
    for (int nt = 0; nt < 2; ++nt) {
      int n_l = nt * 16 + l15;
      ushort4 v;
      v.x = f2b(fmaxf(acc[mtl][nt][0] * sc[0] + bi[0], 0.f));
      v.y = f2b(fmaxf(acc[mtl][nt][1] * sc[1] + bi[1], 0.f));
      v.z = f2b(fmaxf(acc[mtl][nt][2] * sc[2] + bi[2], 0.f));
      v.w = f2b(fmaxf(acc[mtl][nt][3] * sc[3] + bi[3], 0.f));
      *(ushort4*)(&xb1[n_l * 136 + m4]) = v;
    }
  }
  __syncthreads();

  // ---- stage 3: ext2 (K=128), xb1 -> xb0, + residual(xb0), store out0 ----
  gemm32(W2, xb1, l15, lq, wv, acc);
#pragma unroll
  for (int mtl = 0; mtl < 2; ++mtl) {
    int m4 = (wv * 2 + mtl) * 16 + lq * 4;
    f32x4 sc = *(const f32x4*)(st + 2 * 256 + m4);
    f32x4 bi = *(const f32x4*)(st + 2 * 256 + 128 + m4);
#pragma unroll
    for (int nt = 0; nt < 2; ++nt) {
      int n_l = nt * 16 + l15;
      int n_g = n0 + n_l;
      ushort4 xp = *(const ushort4*)(&xb0[n_l * 136 + m4]);
      float v0 = fmaxf(acc[mtl][nt][0] * sc[0] + bi[0] + b2f(xp.x), 0.f);
      float v1 = fmaxf(acc[mtl][nt][1] * sc[1] + bi[1] + b2f(xp.y), 0.f);
      float v2 = fmaxf(acc[mtl][nt][2] * sc[2] + bi[2] + b2f(xp.z), 0.f);
      float v3 = fmaxf(acc[mtl][nt][3] * sc[3] + bi[3] + b2f(xp.w), 0.f);
      ushort4 v;
      v.x = f2b(v0); v.y = f2b(v1); v.z = f2b(v2); v.w = f2b(v3);
      *(ushort4*)(&xb0[n_l * 136 + m4]) = v;
      out[((size_t)(b * C_ + m4 + 0)) * N_ + n_g] = v0;
      out[((size_t)(b * C_ + m4 + 1)) * N_ + n_g] = v1;
      out[((size_t)(b * C_ + m4 + 2)) * N_ + n_g] = v2;
      out[((size_t)(b * C_ + m4 + 3)) * N_ + n_g] = v3;
    }
  }
  __syncthreads();

  // ---- stage 4: pred1 (K=128), xb0 -> xb1, store out1 ([B][N][128]) ----
  gemm32(W3, xb0, l15, lq, wv, acc);
  {
    float* out1 = out + (size_t)B_ * C_ * N_;
#pragma unroll
    for (int mtl = 0; mtl < 2; ++mtl) {
      int m4 = (wv * 2 + mtl) * 16 + lq * 4;
      f32x4 sc = *(const f32x4*)(st + 3 * 256 + m4);
      f32x4 bi = *(const f32x4*)(st + 3 * 256 + 128 + m4);
#pragma unroll
      for (int nt = 0; nt < 2; ++nt) {
        int n_l = nt * 16 + l15;
        int n_g = n0 + n_l;
        float v0 = fmaxf(acc[mtl][nt][0] * sc[0] + bi[0], 0.f);
        float v1 = fmaxf(acc[mtl][nt][1] * sc[1] + bi[1], 0.f);
        float v2 = fmaxf(acc[mtl][nt][2] * sc[2] + bi[2], 0.f);
        float v3 = fmaxf(acc[mtl][nt][3] * sc[3] + bi[3], 0.f);
        ushort4 v;
        v.x = f2b(v0); v.y = f2b(v1); v.z = f2b(v2); v.w = f2b(v3);
        *(ushort4*)(&xb1[n_l * 136 + m4]) = v;
        float4 o4 = make_float4(v0, v1, v2, v3);
        *(float4*)(out1 + ((size_t)(b * N_ + n_g)) * 128 + m4) = o4;
      }
    }
  }
  __syncthreads();

  // ---- stage 5: pred2 (M=13 pad 16, K=128): waves 0,1 each do one nt ----
  if (wv < 2) {
    f32x4 a2 = (f32x4){0.f, 0.f, 0.f, 0.f};
#pragma unroll
    for (int ks = 0; ks < 4; ++ks) {
      int ko = ks * 32 + lq * 8;
      s16x8 b0 = *(const s16x8*)(&xb1[(wv * 16 + l15) * 136 + ko]);
      s16x8 a = *(const s16x8*)(Wp2 + (size_t)l15 * 128 + ko);
      a2 = MFMA16(a, b0, a2);
    }
    float* out2 = out + (size_t)B_ * C_ * N_ + (size_t)B_ * N_ * 128;
    f32x4 sc = *(const f32x4*)(st + 4 * 256 + lq * 4);
    f32x4 bi = *(const f32x4*)(st + 4 * 256 + 128 + lq * 4);
    int n_g = n0 + wv * 16 + l15;
#pragma unroll
    for (int r = 0; r < 4; ++r) {
      int m = lq * 4 + r;
      if (m < OC_) {
        out2[((size_t)(b * N_ + n_g)) * OC_ + m] =
            fmaxf(a2[r] * sc[r] + bi[r], 0.f);
      }
    }
  }
}

// ---------------------------------------------------------------------------
extern "C" void kernel_launch(void* const* d_in, const int* in_sizes, int n_in,
                              void* d_out, int out_size, void* d_ws, size_t ws_size,
                              hipStream_t stream) {
  const float* xyz1      = (const float*)d_in[0];
  const float* xyz2      = (const float*)d_in[1];
  const float* points1   = (const float*)d_in[2];
  const float* points2   = (const float*)d_in[3];
  const float* last_pred = (const float*)d_in[4];
  const float* fuse_W    = (const float*)d_in[5];
  const float* fuse_b    = (const float*)d_in[6];
  const float* fuse_bn   = (const float*)d_in[7];
  const float* ext1_W    = (const float*)d_in[8];
  const float* ext1_b    = (const float*)d_in[9];
  const float* ext1_bn   = (const float*)d_in[10];
  const float* ext2_W    = (const float*)d_in[11];
  const float* ext2_b    = (const float*)d_in[12];
  const float* ext2_bn   = (const float*)d_in[13];
  const float* pred1_W   = (const float*)d_in[14];
  const float* pred1_b   = (const float*)d_in[15];
  const float* pred1_bn  = (const float*)d_in[16];
  const float* pred2_W   = (const float*)d_in[17];
  const float* pred2_b   = (const float*)d_in[18];
  const float* pred2_bn  = (const float*)d_in[19];

  char* ws = (char*)d_ws;
  u16*   npT  = (u16*)(ws + 0);                // 2*16384*128*2 =  8,388,608
  u16*   p2t  = (u16*)(ws + 8388608);          // 2*4096*256*2  =  4,194,304
  u16*   cand = (u16*)(ws + 12582912);         // 2*16384*48*2  =  3,145,728
  u16*   Wf   = (u16*)(ws + 15728640);         // 128*416*2     =    106,496
  u16*   W1   = (u16*)(ws + 15835136);         // 128*128*2     =     32,768
  u16*   W2   = (u16*)(ws + 15867904);         //                     32,768
  u16*   W3   = (u16*)(ws + 15900672);         //                     32,768
  u16*   Wp2  = (u16*)(ws + 15933440);         // 16*128*2      =      4,096
  float* st   = (float*)(ws + 15937536);       // 5*256*4       =      5,120

  setup_scan_kernel<<<dim3(2624), dim3(256), 0, stream>>>(
      xyz1, xyz2, points1, points2,
      fuse_W, fuse_b, fuse_bn, ext1_W, ext1_b, ext1_bn, ext2_W, ext2_b, ext2_bn,
      pred1_W, pred1_b, pred1_bn, pred2_W, pred2_b, pred2_bn,
      cand, npT, p2t, Wf, W1, W2, W3, Wp2, st);

  mega_kernel<<<dim3(N_ / 32, B_), dim3(256), 0, stream>>>(
      xyz1, xyz2, cand, npT, p2t, last_pred,
      Wf, W1, W2, W3, Wp2, st, (float*)d_out);
}